// Round 10
// baseline (45.272 us; speedup 1.0000x reference)
//
#include <hip/hip_runtime.h>
#include <stdint.h>

#define TT 4
#define BB 8192
#define DD 128
#define HH 8
#define DHD 1024
#define BD (BB*DD)       // 1048576
#define TBM (TT*BB)      // 32768
#define VN (TT*BB*HH*DD) // 33554432
#define ON (TT*BB*DD)    // 4194304

typedef unsigned long long u64;
typedef __attribute__((ext_vector_type(8))) short bf16x8;
typedef __attribute__((ext_vector_type(4))) float f32x4;

// ---------------- K1: fused pre-kernel + 3/8 of the v-zero stream --------------------
// Blocks [0,2048): 6 v-zero float4/thread (primes write pipe, no dependency) +
//   shortcut LIF -> bit masks + fast-path out = BN(bp)+x  (proven exact op order).
// Blocks [2048,2304): Wv -> bf16 (RNE) + per-row no-spike acc bounds hb/lb (V only:
//   V never spikes => kv=0 => kv-LIF never fires => a=0 => out is q/k-independent).
__global__ __launch_bounds__(256) void k_pre(
    const float* __restrict__ x,
    const float* __restrict__ Wv,
    const float* __restrict__ bv, const float* __restrict__ gv, const float* __restrict__ betv,
    const float* __restrict__ mv, const float* __restrict__ vv_,
    const float* __restrict__ bp, const float* __restrict__ gp,
    const float* __restrict__ betp, const float* __restrict__ mp,
    const float* __restrict__ vp,
    uint32_t* __restrict__ xs_bits, float* __restrict__ out, float* __restrict__ vout,
    uint16_t* __restrict__ Wb, float* __restrict__ hb, float* __restrict__ lbd,
    int* __restrict__ flag)
{
  const int tx = threadIdx.x;
  const int wv = tx >> 6, lane = tx & 63;
  if (blockIdx.x == 0 && tx == 0) *flag = 0;

  if (blockIdx.x < 2048) {
    // ---- v-zero share: slabs [0, 3145728) of VN/4 float4s ----
    {
      const float4 z4 = {0.f, 0.f, 0.f, 0.f};
      float4* vp4 = (float4*)vout;
      int base = blockIdx.x * 256 + tx;        // 0..524287
#pragma unroll
      for (int j = 0; j < 6; j++)
        vp4[(size_t)j * 524288 + base] = z4;
    }
    // ---- LIF over x + fast-path out ----
    const int b = blockIdx.x * 4 + wv;
    const int d0 = lane, d1 = lane + 64;
    float s0 = gp[d0] / sqrtf(vp[d0] + 1e-5f);
    float c0 = __fadd_rn(__fmul_rn(__fsub_rn(bp[d0], mp[d0]), s0), betp[d0]);
    float s1 = gp[d1] / sqrtf(vp[d1] + 1e-5f);
    float c1 = __fadd_rn(__fmul_rn(__fsub_rn(bp[d1], mp[d1]), s1), betp[d1]);

    float v0 = 0.f, v1 = 0.f;
#pragma unroll
    for (int t = 0; t < TT; t++) {
      size_t base = (size_t)t * BD + (size_t)b * DD;
      float x0 = x[base + d0];
      float x1 = x[base + d1];
      out[base + d0] = __fadd_rn(c0, x0);       // proven exact op order (R4-R9)
      out[base + d1] = __fadd_rn(c1, x1);
      v0 = __fadd_rn(v0, __fmul_rn(__fsub_rn(x0, v0), 0.5f));
      v1 = __fadd_rn(v1, __fmul_rn(__fsub_rn(x1, v1), 0.5f));
      int sp0 = (v0 >= 1.0f) ? 1 : 0;
      int sp1 = (v1 >= 1.0f) ? 1 : 0;
      u64 lo = __ballot(sp0);
      u64 hi = __ballot(sp1);
      if (sp0) v0 = 0.f;
      if (sp1) v1 = 0.f;
      if (lane == 0) {
        u64* p = (u64*)&xs_bits[((size_t)t * BB + b) * 4];
        p[0] = lo;
        p[1] = hi;
      }
    }
  } else {
    const int row = (blockIdx.x - 2048) * 4 + wv;     // 0..1023 (dh of V)
    float d = 0.f;
#pragma unroll
    for (int h = 0; h < 2; h++) {
      int k = lane + 64 * h;
      float w = Wv[(size_t)row * DD + k];
      uint32_t bits = __builtin_bit_cast(uint32_t, w);
      uint32_t r = (bits + 0x7fffu + ((bits >> 16) & 1u)) >> 16;   // RNE to bf16
      Wb[(size_t)row * DD + k] = (uint16_t)r;
      d += fabsf(w - __builtin_bit_cast(float, r << 16));
    }
#pragma unroll
    for (int s2 = 1; s2 < 64; s2 <<= 1) d += __shfl_xor(d, s2);
    if (lane == 0) {
      float sc = gv[row] / sqrtf(vv_[row] + 1e-5f);
      float c1 = (bv[row] - mv[row]) * sc + betv[row];
      float err = fabsf(sc) * d + 1e-3f;
      float B0 = 1.0666f - err;     // no spike iff ymax < 16/15 - err
      float h = 3.0e38f, l = -3.0e38f;
      if (sc > 1e-20f) {
        h = (B0 - c1) / sc - 1e-4f;
      } else if (sc < -1e-20f) {
        l = (B0 - c1) / sc + 1e-4f;
      } else if (c1 >= B0) {
        h = -3.0e38f;
      }
      hb[row] = h;
      lbd[row] = l;
    }
  }
}

// ---------------- K2: V-branch MFMA certificate + remaining 5/8 v-zero stream --------
// Grid (64 M-chunks, 32 N-tiles) = 2048 blocks, 4 waves stacked in M.
// Per half-chunk: load bits (L2), 5 v-zero float4 stores, per-ks register expansion
// of afr[4], 8 MFMA. Covers v-zero slabs [3145728, 8388608).
__global__ __launch_bounds__(256) void k_cert(
    const uint32_t* __restrict__ xs_bits,
    const uint16_t* __restrict__ Wb,
    const float* __restrict__ hb, const float* __restrict__ lbd,
    float* __restrict__ vout, int* __restrict__ flag)
{
  __shared__ short Bs[32 * 128];   // 8 KB

  const int tx = threadIdx.x;
  const int mc = blockIdx.x;                    // 0..63
  const int n0 = blockIdx.y * 32;
  const int lb = blockIdx.x * 32 + blockIdx.y;  // 0..2047
  const int lane = tx & 63, wm = tx >> 6;
  const int l15 = lane & 15, l4 = lane >> 4;
  const int sh = l4 * 8;

  // ---- stage B (swizzled slots: s' = s ^ (n&15)) ----
  {
    const uint4* Wb4 = (const uint4*)Wb;
#pragma unroll
    for (int i = 0; i < 2; i++) {
      int f = tx + i * 256;            // 0..511 = 32 rows x 16 slots
      int n = f >> 4, s = f & 15;
      uint4 w = Wb4[((size_t)(n0 + n)) * 16 + s];
      *(uint4*)&Bs[n * 128 + ((s ^ (n & 15)) << 3)] = w;
    }
  }

  // ---- per-block bounds: min/max over this tile's 32 columns ----
  float hi, lo;
  {
    float h = hb[n0 + (lane & 31)];
    float l = lbd[n0 + (lane & 31)];
#pragma unroll
    for (int s2 = 1; s2 < 32; s2 <<= 1) {
      h = fminf(h, __shfl_xor(h, s2));
      l = fmaxf(l, __shfl_xor(l, s2));
    }
    hi = h; lo = l;
  }

  float mx = -3.0e38f, mn = 3.0e38f;
  const float4 z4 = {0.f, 0.f, 0.f, 0.f};
  __syncthreads();

  for (int it = 0; it < 2; it++) {
    // ---- bits for this half-chunk (4 x 16B, L2-resident) ----
    uint4 bits[4];
    {
      int mrow = mc * 512 + it * 256 + wm * 64;
#pragma unroll
      for (int mf = 0; mf < 4; mf++)
        bits[mf] = ((const uint4*)xs_bits)[mrow + mf * 16 + l15];
    }
    // ---- v-zero share: slabs [3145728, 8388608) ----
#pragma unroll
    for (int j = 0; j < 5; j++) {
      int idx = 3145728 + (it * 5 + j) * 524288 + lb * 256 + tx;
      ((float4*)vout)[idx] = z4;
    }

    f32x4 acc[4][2];
#pragma unroll
    for (int mf = 0; mf < 4; mf++)
#pragma unroll
      for (int nf = 0; nf < 2; nf++) acc[mf][nf] = (f32x4){0.f, 0.f, 0.f, 0.f};

#pragma unroll
    for (int ks = 0; ks < 4; ks++) {
      // ---- expand this ks's A fragments only (16 VGPR live) ----
      bf16x8 afr[4];
#pragma unroll
      for (int mf = 0; mf < 4; mf++) {
        uint32_t wk = (ks == 0) ? bits[mf].x : (ks == 1) ? bits[mf].y
                    : (ks == 2) ? bits[mf].z : bits[mf].w;
        uint32_t by = (wk >> sh) & 0xffu;
        bf16x8 v;
#pragma unroll
        for (int j = 0; j < 8; j++) v[j] = (by & (1u << j)) ? (short)0x3F80 : (short)0;
        afr[mf] = v;
      }
      // ---- 8 MFMA ----
      int s = ks * 4 + l4;
#pragma unroll
      for (int nf = 0; nf < 2; nf++) {
        int n = nf * 16 + l15;
        bf16x8 bfr = *(const bf16x8*)&Bs[n * 128 + ((s ^ (n & 15)) << 3)];
#pragma unroll
        for (int mf = 0; mf < 4; mf++)
          acc[mf][nf] = __builtin_amdgcn_mfma_f32_16x16x32_bf16(afr[mf], bfr,
                                                                acc[mf][nf], 0, 0, 0);
      }
    }
#pragma unroll
    for (int mf = 0; mf < 4; mf++)
#pragma unroll
      for (int nf = 0; nf < 2; nf++) {
        f32x4 a = acc[mf][nf];
        mx = fmaxf(fmaxf(mx, fmaxf(a[0], a[1])), fmaxf(a[2], a[3]));
        mn = fminf(fminf(mn, fminf(a[0], a[1])), fminf(a[2], a[3]));
      }
  }

  bool bad = (mx > hi) || (mn < lo);
  if (__any((int)bad)) {
    if (lane == 0) atomicOr(flag, 1);
  }
}

// ---------------- Fallback (flag!=0): bit-exact sparse pipeline, grid-strided --------
__global__ __launch_bounds__(256) void k_qkv(
    const uint32_t* __restrict__ xs_bits,
    const float* __restrict__ Wq, const float* __restrict__ Wk, const float* __restrict__ Wv,
    const float* __restrict__ bq, const float* __restrict__ gq, const float* __restrict__ betq,
    const float* __restrict__ mq, const float* __restrict__ vq,
    const float* __restrict__ bk, const float* __restrict__ gk, const float* __restrict__ betk,
    const float* __restrict__ mk, const float* __restrict__ vk,
    const float* __restrict__ bv, const float* __restrict__ gv, const float* __restrict__ betv,
    const float* __restrict__ mv, const float* __restrict__ vv_,
    float* __restrict__ vout, uint8_t* __restrict__ a_bytes,
    const int* __restrict__ flag)
{
  if (flag[0] == 0) return;
  __shared__ float W_s[128 * 64];

  const int tx = threadIdx.x;
  const int lane = tx & 63;
  const int grp = tx >> 6;
  const int dh0 = (blockIdx.x & 15) * 64;
  const int ny = dh0 >> 6;
  const int dh = dh0 + lane;

  for (int bc = (int)(blockIdx.x >> 4); bc < 128; bc += 16) {
    const int b0 = bc * 64;

    auto lds_w = [&](int kk) -> float {
      return W_s[(kk << 6) | (lane ^ (kk >> 2))];
    };
    auto scan = [&](u64 m, int base, float a) -> float {
      if (m) {
        int k = __builtin_ctzll(m); m &= m - 1;
        float wv = lds_w(base + k);
        while (m) {
          int k2 = __builtin_ctzll(m); m &= m - 1;
          float wn = lds_w(base + k2);
          a = __fadd_rn(a, wv);
          wv = wn;
        }
        a = __fadd_rn(a, wv);
      }
      return a;
    };

    auto branch = [&](const float* __restrict__ Wg, const float* __restrict__ bb,
                      const float* __restrict__ gg, const float* __restrict__ be,
                      const float* __restrict__ mmp, const float* __restrict__ vvp) -> u64 {
      __syncthreads();
      {
        const float4* Wg4 = (const float4*)(Wg + (size_t)dh0 * DD);
#pragma unroll
        for (int j = 0; j < 8; j++) {
          int idx = tx + j * 256;
          int n = idx >> 5, k4 = idx & 31;
          float4 w = Wg4[n * 32 + k4];
          int kk = k4 * 4;
          int col = n ^ k4;
          W_s[(kk + 0) * 64 + col] = w.x;
          W_s[(kk + 1) * 64 + col] = w.y;
          W_s[(kk + 2) * 64 + col] = w.z;
          W_s[(kk + 3) * 64 + col] = w.w;
        }
      }
      __syncthreads();

      float acc[TT][16];
#pragma unroll
      for (int t = 0; t < TT; t++)
#pragma unroll
        for (int bi = 0; bi < 16; bi++) acc[t][bi] = 0.f;

      const uint4* xb = (const uint4*)xs_bits;
#pragma unroll
      for (int bi = 0; bi < 16; bi++) {
        const int b = b0 + grp * 16 + bi;
#pragma unroll
        for (int t = 0; t < TT; t++) {
          uint4 m4 = xb[(size_t)t * BB + b];
          u64 mlo = ((u64)(uint32_t)__builtin_amdgcn_readfirstlane(m4.y) << 32) |
                    (uint32_t)__builtin_amdgcn_readfirstlane(m4.x);
          u64 mhi = ((u64)(uint32_t)__builtin_amdgcn_readfirstlane(m4.w) << 32) |
                    (uint32_t)__builtin_amdgcn_readfirstlane(m4.z);
          float a = acc[t][bi];
          a = scan(mlo, 0, a);
          a = scan(mhi, 64, a);
          acc[t][bi] = a;
        }
      }

      float bias = bb[dh];
      float sc = gg[dh] / sqrtf(vvp[dh] + 1e-5f);
      float mmv = mmp[dh];
      float bev = be[dh];
      u64 bits = 0;
#pragma unroll
      for (int bi = 0; bi < 16; bi++) {
        float u = 0.f;
#pragma unroll
        for (int t = 0; t < TT; t++) {
          float y = __fadd_rn(acc[t][bi], bias);
          y = __fadd_rn(__fmul_rn(__fsub_rn(y, mmv), sc), bev);
          u = __fadd_rn(u, __fmul_rn(__fsub_rn(y, u), 0.5f));
          if (u >= 1.0f) { bits |= (1ull << (t * 16 + bi)); u = 0.f; }
        }
      }
      return bits;
    };

    u64 qb = branch(Wq, bq, gq, betq, mq, vq);
    u64 kb = branch(Wk, bk, gk, betk, mk, vk);
    u64 vb = branch(Wv, bv, gv, betv, mv, vv_);

    const int hh2 = lane & 7;
    const int dg = (dh0 >> 3) + (lane >> 3);
#pragma unroll
    for (int t = 0; t < TT; t++) {
#pragma unroll
      for (int bi = 0; bi < 16; bi++) {
        float s = (float)((vb >> (t * 16 + bi)) & 1ull);
        vout[(((size_t)t * BB + (b0 + grp * 16 + bi)) * HH + hh2) * DD + dg] = s;
      }
    }

    u64 kvand = kb & vb;
    u64 ab = 0;
#pragma unroll
    for (int bi = 0; bi < 16; bi++) {
      float u = 0.f;
#pragma unroll
      for (int t = 0; t < TT; t++) {
        float kvf = (float)((kvand >> (t * 16 + bi)) & 1ull);
        kvf += __shfl_xor(kvf, 1);
        kvf += __shfl_xor(kvf, 2);
        kvf += __shfl_xor(kvf, 4);
        u = u + (kvf - u) * 0.5f;
        uint32_t s = (u >= 0.5f) ? 1u : 0u;
        if (s) u = 0.f;
        uint32_t qbit = (uint32_t)((qb >> (t * 16 + bi)) & 1ull);
        ab |= (u64)(qbit & s) << (t * 16 + bi);
      }
    }

#pragma unroll
    for (int t = 0; t < TT; t++) {
#pragma unroll
      for (int bi = 0; bi < 16; bi++) {
        u64 msk = __ballot((int)((ab >> (t * 16 + bi)) & 1ull));
        if (lane < 8) {
          uint32_t byte = 0;
#pragma unroll
          for (int d2 = 0; d2 < 8; d2++)
            byte |= (uint32_t)((msk >> (d2 * 8 + lane)) & 1ull) << d2;
          a_bytes[((size_t)t * BB + (b0 + grp * 16 + bi)) * 128 + lane * 16 + ny] =
              (uint8_t)byte;
        }
      }
    }
  }
}

__global__ __launch_bounds__(256) void k_out(
    const uint8_t* __restrict__ a_bytes,
    const float* __restrict__ Wp, const float* __restrict__ bp2,
    const float* __restrict__ gp, const float* __restrict__ betp,
    const float* __restrict__ mp, const float* __restrict__ vp,
    const float* __restrict__ x, float* __restrict__ out,
    const int* __restrict__ flag)
{
  if (flag[0] == 0) return;
  const int wv = threadIdx.x >> 6, lane = threadIdx.x & 63;

  for (size_t m = (size_t)blockIdx.x * 4 + wv; m < TBM; m += (size_t)gridDim.x * 4) {
    const uint4* aw = (const uint4*)(a_bytes + m * 128);
    float acc0 = 0.f, acc1 = 0.f;
#pragma unroll
    for (int q4 = 0; q4 < 8; q4++) {
      uint4 mq = aw[q4];
      uint32_t ws[4];
      ws[0] = (uint32_t)__builtin_amdgcn_readfirstlane(mq.x);
      ws[1] = (uint32_t)__builtin_amdgcn_readfirstlane(mq.y);
      ws[2] = (uint32_t)__builtin_amdgcn_readfirstlane(mq.z);
      ws[3] = (uint32_t)__builtin_amdgcn_readfirstlane(mq.w);
#pragma unroll
      for (int w = 0; w < 4; w++) {
        uint32_t mm = ws[w];
        while (mm) {
          int kb = __builtin_ctz(mm); mm &= mm - 1;
          int k = q4 * 128 + w * 32 + kb;
          acc0 = __fadd_rn(acc0, Wp[(size_t)lane * DHD + k]);
          acc1 = __fadd_rn(acc1, Wp[(size_t)(lane + 64) * DHD + k]);
        }
      }
    }

#pragma unroll
    for (int half = 0; half < 2; half++) {
      int j = lane + half * 64;
      float acc = half ? acc1 : acc0;
      float scp = gp[j] / sqrtf(vp[j] + 1e-5f);
      float y = __fadd_rn(acc, bp2[j]);
      y = __fadd_rn(__fmul_rn(__fsub_rn(y, mp[j]), scp), betp[j]);
      y = __fadd_rn(y, x[m * DD + j]);
      out[m * DD + j] = y;
    }
  }
}

// ---------------- launch ----------------
extern "C" void kernel_launch(void* const* d_in, const int* in_sizes, int n_in,
                              void* d_out, int out_size, void* d_ws, size_t ws_size,
                              hipStream_t stream) {
  const float* x    = (const float*)d_in[0];
  const float* Wq   = (const float*)d_in[1];
  const float* Wk   = (const float*)d_in[2];
  const float* Wv   = (const float*)d_in[3];
  const float* Wp   = (const float*)d_in[4];
  const float* bq   = (const float*)d_in[5];
  const float* gq   = (const float*)d_in[6];
  const float* betq = (const float*)d_in[7];
  const float* mq   = (const float*)d_in[8];
  const float* vq   = (const float*)d_in[9];
  const float* bk   = (const float*)d_in[10];
  const float* gk   = (const float*)d_in[11];
  const float* betk = (const float*)d_in[12];
  const float* mk   = (const float*)d_in[13];
  const float* vk   = (const float*)d_in[14];
  const float* bv   = (const float*)d_in[15];
  const float* gv   = (const float*)d_in[16];
  const float* betv = (const float*)d_in[17];
  const float* mv   = (const float*)d_in[18];
  const float* vv   = (const float*)d_in[19];
  const float* bp   = (const float*)d_in[20];
  const float* gp   = (const float*)d_in[21];
  const float* betp = (const float*)d_in[22];
  const float* mp   = (const float*)d_in[23];
  const float* vp   = (const float*)d_in[24];

  float* out  = (float*)d_out;
  float* vout = out + (size_t)ON;

  uint8_t* ws = (uint8_t*)d_ws;
  uint32_t* xs_bits = (uint32_t*)ws;                        // 512 KB
  uint8_t*  a_bytes = ws + 524288;                          // 4 MB
  uint16_t* Wb      = (uint16_t*)(ws + 4718592);            // 256 KB (V only)
  float*    hb      = (float*)(ws + 4980736);               // 4 KB
  float*    lbd     = (float*)(ws + 4984832);               // 4 KB
  int*      flag    = (int*)(ws + 4988928);                 // 4 B

  k_pre<<<2304, 256, 0, stream>>>(x, Wv,
                                  bv, gv, betv, mv, vv,
                                  bp, gp, betp, mp, vp,
                                  xs_bits, out, vout, Wb, hb, lbd, flag);

  dim3 gc(64, 32);
  k_cert<<<gc, 256, 0, stream>>>(xs_bits, Wb, hb, lbd, vout, flag);

  k_qkv<<<256, 256, 0, stream>>>(xs_bits, Wq, Wk, Wv,
                                 bq, gq, betq, mq, vq,
                                 bk, gk, betk, mk, vk,
                                 bv, gv, betv, mv, vv,
                                 vout, a_bytes, flag);

  k_out<<<256, 256, 0, stream>>>(a_bytes, Wp, bp, gp, betp, mp, vp, x, out, flag);
}

// Round 11
// 39.130 us; speedup vs baseline: 1.1570x; 1.1570x over previous
//
#include <hip/hip_runtime.h>
#include <stdint.h>

#define TT 4
#define BB 8192
#define DD 128
#define HH 8
#define DHD 1024
#define BD (BB*DD)       // 1048576
#define TBM (TT*BB)      // 32768
#define VN (TT*BB*HH*DD) // 33554432
#define ON (TT*BB*DD)    // 4194304

typedef unsigned long long u64;
typedef __attribute__((ext_vector_type(8))) short bf16x8;
typedef __attribute__((ext_vector_type(4))) float f32x4;

// ---------------- K1: fused pre-kernel (R7/R9 proven structure) ----------------------
// Blocks [0,2048): shortcut LIF -> bit masks + fast-path out = BN(bp)+x
// Blocks [2048,2304): Wv -> bf16 (RNE) + per-row no-spike acc bounds hb/lb (V only:
//   V never spikes => kv=0 => kv-LIF never fires => a=0 => out is q/k-independent).
__global__ __launch_bounds__(256) void k_pre(
    const float* __restrict__ x,
    const float* __restrict__ Wv,
    const float* __restrict__ bv, const float* __restrict__ gv, const float* __restrict__ betv,
    const float* __restrict__ mv, const float* __restrict__ vv_,
    const float* __restrict__ bp, const float* __restrict__ gp,
    const float* __restrict__ betp, const float* __restrict__ mp,
    const float* __restrict__ vp,
    uint32_t* __restrict__ xs_bits, float* __restrict__ out,
    uint16_t* __restrict__ Wb, float* __restrict__ hb, float* __restrict__ lbd,
    int* __restrict__ flag)
{
  const int wv = threadIdx.x >> 6, lane = threadIdx.x & 63;
  if (blockIdx.x == 0 && threadIdx.x == 0) *flag = 0;

  if (blockIdx.x < 2048) {
    const int b = blockIdx.x * 4 + wv;
    const int d0 = lane, d1 = lane + 64;
    float s0 = gp[d0] / sqrtf(vp[d0] + 1e-5f);
    float c0 = __fadd_rn(__fmul_rn(__fsub_rn(bp[d0], mp[d0]), s0), betp[d0]);
    float s1 = gp[d1] / sqrtf(vp[d1] + 1e-5f);
    float c1 = __fadd_rn(__fmul_rn(__fsub_rn(bp[d1], mp[d1]), s1), betp[d1]);

    float v0 = 0.f, v1 = 0.f;
#pragma unroll
    for (int t = 0; t < TT; t++) {
      size_t base = (size_t)t * BD + (size_t)b * DD;
      float x0 = x[base + d0];
      float x1 = x[base + d1];
      out[base + d0] = __fadd_rn(c0, x0);       // proven exact op order (R4-R9)
      out[base + d1] = __fadd_rn(c1, x1);
      v0 = __fadd_rn(v0, __fmul_rn(__fsub_rn(x0, v0), 0.5f));
      v1 = __fadd_rn(v1, __fmul_rn(__fsub_rn(x1, v1), 0.5f));
      int sp0 = (v0 >= 1.0f) ? 1 : 0;
      int sp1 = (v1 >= 1.0f) ? 1 : 0;
      u64 lo = __ballot(sp0);
      u64 hi = __ballot(sp1);
      if (sp0) v0 = 0.f;
      if (sp1) v1 = 0.f;
      if (lane == 0) {
        u64* p = (u64*)&xs_bits[((size_t)t * BB + b) * 4];
        p[0] = lo;
        p[1] = hi;
      }
    }
  } else {
    const int row = (blockIdx.x - 2048) * 4 + wv;     // 0..1023 (dh of V)
    float d = 0.f;
#pragma unroll
    for (int h = 0; h < 2; h++) {
      int k = lane + 64 * h;
      float w = Wv[(size_t)row * DD + k];
      uint32_t bits = __builtin_bit_cast(uint32_t, w);
      uint32_t r = (bits + 0x7fffu + ((bits >> 16) & 1u)) >> 16;   // RNE to bf16
      Wb[(size_t)row * DD + k] = (uint16_t)r;
      d += fabsf(w - __builtin_bit_cast(float, r << 16));
    }
#pragma unroll
    for (int s2 = 1; s2 < 64; s2 <<= 1) d += __shfl_xor(d, s2);
    if (lane == 0) {
      float sc = gv[row] / sqrtf(vv_[row] + 1e-5f);
      float c1 = (bv[row] - mv[row]) * sc + betv[row];
      float err = fabsf(sc) * d + 1e-3f;
      float B0 = 1.0666f - err;     // no spike iff ymax < 16/15 - err
      float h = 3.0e38f, l = -3.0e38f;
      if (sc > 1e-20f) {
        h = (B0 - c1) / sc - 1e-4f;
      } else if (sc < -1e-20f) {
        l = (B0 - c1) / sc + 1e-4f;
      } else if (c1 >= B0) {
        h = -3.0e38f;
      }
      hb[row] = h;
      lbd[row] = l;
    }
  }
}

// ---------------- K2: V-branch MFMA certificate + interleaved v-zero stream ----------
// Grid (64 M-chunks, 32 N-tiles) = 2048 blocks, 4 waves stacked in M.
// Per half-chunk: load bits (L2), issue 8 v-zero float4 stores to prime the write
// pipe, then per-ks expand afr[4] in registers (16 VGPR live) and run 8 MFMA.
// Measured at ~6.9 TB/s = the streaming-store ceiling (R9).
__global__ __launch_bounds__(256) void k_cert(
    const uint32_t* __restrict__ xs_bits,
    const uint16_t* __restrict__ Wb,
    const float* __restrict__ hb, const float* __restrict__ lbd,
    float* __restrict__ vout, int* __restrict__ flag)
{
  __shared__ short Bs[32 * 128];   // 8 KB

  const int tx = threadIdx.x;
  const int mc = blockIdx.x;                    // 0..63
  const int n0 = blockIdx.y * 32;
  const int lb = blockIdx.x * 32 + blockIdx.y;  // 0..2047
  const int lane = tx & 63, wm = tx >> 6;
  const int l15 = lane & 15, l4 = lane >> 4;
  const int sh = l4 * 8;

  // ---- stage B (swizzled slots: s' = s ^ (n&15)) ----
  {
    const uint4* Wb4 = (const uint4*)Wb;
#pragma unroll
    for (int i = 0; i < 2; i++) {
      int f = tx + i * 256;            // 0..511 = 32 rows x 16 slots
      int n = f >> 4, s = f & 15;
      uint4 w = Wb4[((size_t)(n0 + n)) * 16 + s];
      *(uint4*)&Bs[n * 128 + ((s ^ (n & 15)) << 3)] = w;
    }
  }

  // ---- per-block bounds: min/max over this tile's 32 columns ----
  float hi, lo;
  {
    float h = hb[n0 + (lane & 31)];
    float l = lbd[n0 + (lane & 31)];
#pragma unroll
    for (int s2 = 1; s2 < 32; s2 <<= 1) {
      h = fminf(h, __shfl_xor(h, s2));
      l = fmaxf(l, __shfl_xor(l, s2));
    }
    hi = h; lo = l;
  }

  float mx = -3.0e38f, mn = 3.0e38f;
  const float4 z4 = {0.f, 0.f, 0.f, 0.f};
  __syncthreads();

  for (int it = 0; it < 2; it++) {
    // ---- bits for this half-chunk (4 x 16B, L2-resident) ----
    uint4 bits[4];
    {
      int mrow = mc * 512 + it * 256 + wm * 64;
#pragma unroll
      for (int mf = 0; mf < 4; mf++)
        bits[mf] = ((const uint4*)xs_bits)[mrow + mf * 16 + l15];
    }
    // ---- prime the write pipe: 8 v-zero float4 stores ----
#pragma unroll
    for (int j = 0; j < 8; j++) {
      int idx = (it * 8 + j) * 524288 + lb * 256 + tx;   // covers VN/4 exactly
      ((float4*)vout)[idx] = z4;
    }

    f32x4 acc[4][2];
#pragma unroll
    for (int mf = 0; mf < 4; mf++)
#pragma unroll
      for (int nf = 0; nf < 2; nf++) acc[mf][nf] = (f32x4){0.f, 0.f, 0.f, 0.f};

#pragma unroll
    for (int ks = 0; ks < 4; ks++) {
      // ---- expand this ks's A fragments only (16 VGPR live) ----
      bf16x8 afr[4];
#pragma unroll
      for (int mf = 0; mf < 4; mf++) {
        uint32_t wk = (ks == 0) ? bits[mf].x : (ks == 1) ? bits[mf].y
                    : (ks == 2) ? bits[mf].z : bits[mf].w;
        uint32_t by = (wk >> sh) & 0xffu;
        bf16x8 v;
#pragma unroll
        for (int j = 0; j < 8; j++) v[j] = (by & (1u << j)) ? (short)0x3F80 : (short)0;
        afr[mf] = v;
      }
      // ---- 8 MFMA ----
      int s = ks * 4 + l4;
#pragma unroll
      for (int nf = 0; nf < 2; nf++) {
        int n = nf * 16 + l15;
        bf16x8 bfr = *(const bf16x8*)&Bs[n * 128 + ((s ^ (n & 15)) << 3)];
#pragma unroll
        for (int mf = 0; mf < 4; mf++)
          acc[mf][nf] = __builtin_amdgcn_mfma_f32_16x16x32_bf16(afr[mf], bfr,
                                                                acc[mf][nf], 0, 0, 0);
      }
    }
#pragma unroll
    for (int mf = 0; mf < 4; mf++)
#pragma unroll
      for (int nf = 0; nf < 2; nf++) {
        f32x4 a = acc[mf][nf];
        mx = fmaxf(fmaxf(mx, fmaxf(a[0], a[1])), fmaxf(a[2], a[3]));
        mn = fminf(fminf(mn, fminf(a[0], a[1])), fminf(a[2], a[3]));
      }
  }

  bool bad = (mx > hi) || (mn < lo);
  if (__any((int)bad)) {
    if (lane == 0) atomicOr(flag, 1);
  }
}

// ---------------- Fallback (flag!=0): bit-exact sparse pipeline, grid-strided --------
__global__ __launch_bounds__(256) void k_qkv(
    const uint32_t* __restrict__ xs_bits,
    const float* __restrict__ Wq, const float* __restrict__ Wk, const float* __restrict__ Wv,
    const float* __restrict__ bq, const float* __restrict__ gq, const float* __restrict__ betq,
    const float* __restrict__ mq, const float* __restrict__ vq,
    const float* __restrict__ bk, const float* __restrict__ gk, const float* __restrict__ betk,
    const float* __restrict__ mk, const float* __restrict__ vk,
    const float* __restrict__ bv, const float* __restrict__ gv, const float* __restrict__ betv,
    const float* __restrict__ mv, const float* __restrict__ vv_,
    float* __restrict__ vout, uint8_t* __restrict__ a_bytes,
    const int* __restrict__ flag)
{
  if (flag[0] == 0) return;
  __shared__ float W_s[128 * 64];

  const int tx = threadIdx.x;
  const int lane = tx & 63;
  const int grp = tx >> 6;
  const int dh0 = (blockIdx.x & 15) * 64;
  const int ny = dh0 >> 6;
  const int dh = dh0 + lane;

  for (int bc = (int)(blockIdx.x >> 4); bc < 128; bc += 16) {
    const int b0 = bc * 64;

    auto lds_w = [&](int kk) -> float {
      return W_s[(kk << 6) | (lane ^ (kk >> 2))];
    };
    auto scan = [&](u64 m, int base, float a) -> float {
      if (m) {
        int k = __builtin_ctzll(m); m &= m - 1;
        float wv = lds_w(base + k);
        while (m) {
          int k2 = __builtin_ctzll(m); m &= m - 1;
          float wn = lds_w(base + k2);
          a = __fadd_rn(a, wv);
          wv = wn;
        }
        a = __fadd_rn(a, wv);
      }
      return a;
    };

    auto branch = [&](const float* __restrict__ Wg, const float* __restrict__ bb,
                      const float* __restrict__ gg, const float* __restrict__ be,
                      const float* __restrict__ mmp, const float* __restrict__ vvp) -> u64 {
      __syncthreads();
      {
        const float4* Wg4 = (const float4*)(Wg + (size_t)dh0 * DD);
#pragma unroll
        for (int j = 0; j < 8; j++) {
          int idx = tx + j * 256;
          int n = idx >> 5, k4 = idx & 31;
          float4 w = Wg4[n * 32 + k4];
          int kk = k4 * 4;
          int col = n ^ k4;
          W_s[(kk + 0) * 64 + col] = w.x;
          W_s[(kk + 1) * 64 + col] = w.y;
          W_s[(kk + 2) * 64 + col] = w.z;
          W_s[(kk + 3) * 64 + col] = w.w;
        }
      }
      __syncthreads();

      float acc[TT][16];
#pragma unroll
      for (int t = 0; t < TT; t++)
#pragma unroll
        for (int bi = 0; bi < 16; bi++) acc[t][bi] = 0.f;

      const uint4* xb = (const uint4*)xs_bits;
#pragma unroll
      for (int bi = 0; bi < 16; bi++) {
        const int b = b0 + grp * 16 + bi;
#pragma unroll
        for (int t = 0; t < TT; t++) {
          uint4 m4 = xb[(size_t)t * BB + b];
          u64 mlo = ((u64)(uint32_t)__builtin_amdgcn_readfirstlane(m4.y) << 32) |
                    (uint32_t)__builtin_amdgcn_readfirstlane(m4.x);
          u64 mhi = ((u64)(uint32_t)__builtin_amdgcn_readfirstlane(m4.w) << 32) |
                    (uint32_t)__builtin_amdgcn_readfirstlane(m4.z);
          float a = acc[t][bi];
          a = scan(mlo, 0, a);
          a = scan(mhi, 64, a);
          acc[t][bi] = a;
        }
      }

      float bias = bb[dh];
      float sc = gg[dh] / sqrtf(vvp[dh] + 1e-5f);
      float mmv = mmp[dh];
      float bev = be[dh];
      u64 bits = 0;
#pragma unroll
      for (int bi = 0; bi < 16; bi++) {
        float u = 0.f;
#pragma unroll
        for (int t = 0; t < TT; t++) {
          float y = __fadd_rn(acc[t][bi], bias);
          y = __fadd_rn(__fmul_rn(__fsub_rn(y, mmv), sc), bev);
          u = __fadd_rn(u, __fmul_rn(__fsub_rn(y, u), 0.5f));
          if (u >= 1.0f) { bits |= (1ull << (t * 16 + bi)); u = 0.f; }
        }
      }
      return bits;
    };

    u64 qb = branch(Wq, bq, gq, betq, mq, vq);
    u64 kb = branch(Wk, bk, gk, betk, mk, vk);
    u64 vb = branch(Wv, bv, gv, betv, mv, vv_);

    const int hh2 = lane & 7;
    const int dg = (dh0 >> 3) + (lane >> 3);
#pragma unroll
    for (int t = 0; t < TT; t++) {
#pragma unroll
      for (int bi = 0; bi < 16; bi++) {
        float s = (float)((vb >> (t * 16 + bi)) & 1ull);
        vout[(((size_t)t * BB + (b0 + grp * 16 + bi)) * HH + hh2) * DD + dg] = s;
      }
    }

    u64 kvand = kb & vb;
    u64 ab = 0;
#pragma unroll
    for (int bi = 0; bi < 16; bi++) {
      float u = 0.f;
#pragma unroll
      for (int t = 0; t < TT; t++) {
        float kvf = (float)((kvand >> (t * 16 + bi)) & 1ull);
        kvf += __shfl_xor(kvf, 1);
        kvf += __shfl_xor(kvf, 2);
        kvf += __shfl_xor(kvf, 4);
        u = u + (kvf - u) * 0.5f;
        uint32_t s = (u >= 0.5f) ? 1u : 0u;
        if (s) u = 0.f;
        uint32_t qbit = (uint32_t)((qb >> (t * 16 + bi)) & 1ull);
        ab |= (u64)(qbit & s) << (t * 16 + bi);
      }
    }

#pragma unroll
    for (int t = 0; t < TT; t++) {
#pragma unroll
      for (int bi = 0; bi < 16; bi++) {
        u64 msk = __ballot((int)((ab >> (t * 16 + bi)) & 1ull));
        if (lane < 8) {
          uint32_t byte = 0;
#pragma unroll
          for (int d2 = 0; d2 < 8; d2++)
            byte |= (uint32_t)((msk >> (d2 * 8 + lane)) & 1ull) << d2;
          a_bytes[((size_t)t * BB + (b0 + grp * 16 + bi)) * 128 + lane * 16 + ny] =
              (uint8_t)byte;
        }
      }
    }
  }
}

__global__ __launch_bounds__(256) void k_out(
    const uint8_t* __restrict__ a_bytes,
    const float* __restrict__ Wp, const float* __restrict__ bp2,
    const float* __restrict__ gp, const float* __restrict__ betp,
    const float* __restrict__ mp, const float* __restrict__ vp,
    const float* __restrict__ x, float* __restrict__ out,
    const int* __restrict__ flag)
{
  if (flag[0] == 0) return;
  const int wv = threadIdx.x >> 6, lane = threadIdx.x & 63;

  for (size_t m = (size_t)blockIdx.x * 4 + wv; m < TBM; m += (size_t)gridDim.x * 4) {
    const uint4* aw = (const uint4*)(a_bytes + m * 128);
    float acc0 = 0.f, acc1 = 0.f;
#pragma unroll
    for (int q4 = 0; q4 < 8; q4++) {
      uint4 mq = aw[q4];
      uint32_t ws[4];
      ws[0] = (uint32_t)__builtin_amdgcn_readfirstlane(mq.x);
      ws[1] = (uint32_t)__builtin_amdgcn_readfirstlane(mq.y);
      ws[2] = (uint32_t)__builtin_amdgcn_readfirstlane(mq.z);
      ws[3] = (uint32_t)__builtin_amdgcn_readfirstlane(mq.w);
#pragma unroll
      for (int w = 0; w < 4; w++) {
        uint32_t mm = ws[w];
        while (mm) {
          int kb = __builtin_ctz(mm); mm &= mm - 1;
          int k = q4 * 128 + w * 32 + kb;
          acc0 = __fadd_rn(acc0, Wp[(size_t)lane * DHD + k]);
          acc1 = __fadd_rn(acc1, Wp[(size_t)(lane + 64) * DHD + k]);
        }
      }
    }

#pragma unroll
    for (int half = 0; half < 2; half++) {
      int j = lane + half * 64;
      float acc = half ? acc1 : acc0;
      float scp = gp[j] / sqrtf(vp[j] + 1e-5f);
      float y = __fadd_rn(acc, bp2[j]);
      y = __fadd_rn(__fmul_rn(__fsub_rn(y, mp[j]), scp), betp[j]);
      y = __fadd_rn(y, x[m * DD + j]);
      out[m * DD + j] = y;
    }
  }
}

// ---------------- launch ----------------
extern "C" void kernel_launch(void* const* d_in, const int* in_sizes, int n_in,
                              void* d_out, int out_size, void* d_ws, size_t ws_size,
                              hipStream_t stream) {
  const float* x    = (const float*)d_in[0];
  const float* Wq   = (const float*)d_in[1];
  const float* Wk   = (const float*)d_in[2];
  const float* Wv   = (const float*)d_in[3];
  const float* Wp   = (const float*)d_in[4];
  const float* bq   = (const float*)d_in[5];
  const float* gq   = (const float*)d_in[6];
  const float* betq = (const float*)d_in[7];
  const float* mq   = (const float*)d_in[8];
  const float* vq   = (const float*)d_in[9];
  const float* bk   = (const float*)d_in[10];
  const float* gk   = (const float*)d_in[11];
  const float* betk = (const float*)d_in[12];
  const float* mk   = (const float*)d_in[13];
  const float* vk   = (const float*)d_in[14];
  const float* bv   = (const float*)d_in[15];
  const float* gv   = (const float*)d_in[16];
  const float* betv = (const float*)d_in[17];
  const float* mv   = (const float*)d_in[18];
  const float* vv   = (const float*)d_in[19];
  const float* bp   = (const float*)d_in[20];
  const float* gp   = (const float*)d_in[21];
  const float* betp = (const float*)d_in[22];
  const float* mp   = (const float*)d_in[23];
  const float* vp   = (const float*)d_in[24];

  float* out  = (float*)d_out;
  float* vout = out + (size_t)ON;

  uint8_t* ws = (uint8_t*)d_ws;
  uint32_t* xs_bits = (uint32_t*)ws;                        // 512 KB
  uint8_t*  a_bytes = ws + 524288;                          // 4 MB
  uint16_t* Wb      = (uint16_t*)(ws + 4718592);            // 256 KB (V only)
  float*    hb      = (float*)(ws + 4980736);               // 4 KB
  float*    lbd     = (float*)(ws + 4984832);               // 4 KB
  int*      flag    = (int*)(ws + 4988928);                 // 4 B

  k_pre<<<2304, 256, 0, stream>>>(x, Wv,
                                  bv, gv, betv, mv, vv,
                                  bp, gp, betp, mp, vp,
                                  xs_bits, out, Wb, hb, lbd, flag);

  dim3 gc(64, 32);
  k_cert<<<gc, 256, 0, stream>>>(xs_bits, Wb, hb, lbd, vout, flag);

  k_qkv<<<256, 256, 0, stream>>>(xs_bits, Wq, Wk, Wv,
                                 bq, gq, betq, mq, vq,
                                 bk, gk, betk, mk, vk,
                                 bv, gv, betv, mv, vv,
                                 vout, a_bytes, flag);

  k_out<<<256, 256, 0, stream>>>(a_bytes, Wp, bp, gp, betp, mp, vp, x, out, flag);
}